// Round 11
// baseline (85.545 us; speedup 1.0000x reference)
//
#include <hip/hip_runtime.h>
#include <math.h>

#define NPTS 10000
#define XPT 4              // x-points per thread (register-safe; XPT>=6 hits
                           // a persistent ~2x register-shuffle tax: R3/R9)
#define AXCH 10            // 10 * 256 * 4 = 10240 >= 10000
#define NS 40              // slices  (R2-measured geometry: ~27us)
#define SLICE 250          // NPTS / NS

// ---------------------------------------------------------------------------
// Pass A (exact R2-measured structure): per (combo, slice, x-chunk) max of
// m_j = dot(x,y_j) - 0.5*|y_j|^2  (equiv. min d2). All-scalar fmaf + max3,
// single LDS stage of the 250-y slice, broadcast b128 reads (conflict-free).
// ---------------------------------------------------------------------------
__global__ __launch_bounds__(256) void knn_max(
    const float* __restrict__ pred_pts, const float* __restrict__ targ_pts,
    float* __restrict__ wsM)
{
    const int c   = blockIdx.z;
    const int dir = c >> 1, b = c & 1;
    const float* xp = (dir == 0 ? targ_pts : pred_pts) + (size_t)b * NPTS * 3;
    const float* yp = (dir == 0 ? pred_pts : targ_pts) + (size_t)b * NPTS * 3;
    const int s = blockIdx.y;
    const int base = blockIdx.x * (256 * XPT) + threadIdx.x;

    __shared__ float4 sy[SLICE];               // 4 KB

    float xx[XPT][3];
#pragma unroll
    for (int k = 0; k < XPT; ++k) {
        const int n = base + k * 256;
        const int nn = (n < NPTS) ? n : (NPTS - 1);   // clamp; discard on store
        xx[k][0] = xp[nn * 3 + 0];
        xx[k][1] = xp[nn * 3 + 1];
        xx[k][2] = xp[nn * 3 + 2];
    }
    float best[XPT];
#pragma unroll
    for (int k = 0; k < XPT; ++k) best[k] = -1e30f;

    const int js = s * SLICE;
    if (threadIdx.x < SLICE) {
        const int j = js + threadIdx.x;
        const float a  = yp[j * 3 + 0];
        const float bb = yp[j * 3 + 1];
        const float cc = yp[j * 3 + 2];
        // hy with explicit fmaf chain so finalize reproduces it bit-exactly.
        sy[threadIdx.x] =
            make_float4(a, bb, cc, -0.5f * fmaf(cc, cc, fmaf(bb, bb, a * a)));
    }
    __syncthreads();

#pragma unroll 4
    for (int j = 0; j < SLICE; j += 2) {
        const float4 Y0 = sy[j];               // broadcast: conflict-free
        const float4 Y1 = sy[j + 1];
#pragma unroll
        for (int k = 0; k < XPT; ++k) {
            const float ma = fmaf(xx[k][0], Y0.x,
                             fmaf(xx[k][1], Y0.y,
                             fmaf(xx[k][2], Y0.z, Y0.w)));
            const float mb = fmaf(xx[k][0], Y1.x,
                             fmaf(xx[k][1], Y1.y,
                             fmaf(xx[k][2], Y1.z, Y1.w)));
            best[k] = fmaxf(fmaxf(best[k], ma), mb);   // -> v_max3_f32
        }
    }

#pragma unroll
    for (int k = 0; k < XPT; ++k) {
        const int n = base + k * 256;
        if (n < NPTS)
            wsM[((size_t)c * NS + s) * NPTS + n] = best[k];   // coalesced
    }
}

// ---------------------------------------------------------------------------
// Pass B (R3-proven shape, reduce fused): 8-lane group per x-point.
//   1) slice-select: strided loads (5 iters), butterfly, tie -> smaller s.
//   2) lane-parallel rescan of the winning slice (identical fmaf chain ->
//      bit-consistent with pass A; strict > ascending j, cross-lane tie ->
//      smaller j == exact first-occurrence argmax).
//   3) lane 0: Welsch + normal-cosine terms, PRE-SCALED; block-reduce;
//      one atomicAdd per block per output (out pre-zeroed by memsetAsync).
// ---------------------------------------------------------------------------
__global__ __launch_bounds__(256) void finalize(
    const float* __restrict__ pred_pts, const float* __restrict__ pred_nrm,
    const float* __restrict__ targ_pts, const float* __restrict__ targ_nrm,
    const float* __restrict__ wsM, float* __restrict__ out)
{
    const int c   = blockIdx.y;
    const int dir = c >> 1, b = c & 1;
    const float* xp = (dir == 0 ? targ_pts : pred_pts) + (size_t)b * NPTS * 3;
    const float* xn = (dir == 0 ? targ_nrm : pred_nrm) + (size_t)b * NPTS * 3;
    const float* yp = (dir == 0 ? pred_pts : targ_pts) + (size_t)b * NPTS * 3;
    const float* yn = (dir == 0 ? pred_nrm : targ_nrm) + (size_t)b * NPTS * 3;

    const int lane = threadIdx.x & 7;
    const int n = blockIdx.x * 32 + (threadIdx.x >> 3);

    float t0 = 0.f, t1 = 0.f;
    if (n < NPTS) {
        // 1) slice select
        float bm = -1e30f;
        int   bs = 1 << 30;
        for (int s = lane; s < NS; s += 8) {
            const float m = wsM[((size_t)c * NS + s) * NPTS + n];
            if (m > bm) { bm = m; bs = s; }    // in-lane: s ascending
        }
#pragma unroll
        for (int w = 1; w < 8; w <<= 1) {
            const float mo = __shfl_xor(bm, w);
            const int   so = __shfl_xor(bs, w);
            if (mo > bm || (mo == bm && so < bs)) { bm = mo; bs = so; }
        }
        // 2) rescan winning slice
        const float a  = xp[n * 3 + 0];
        const float bb = xp[n * 3 + 1];
        const float cc = xp[n * 3 + 2];
        const int j0 = bs * SLICE;
        float rb = -1e30f;
        int bidx = 1 << 30;
        for (int j = j0 + lane; j < j0 + SLICE; j += 8) {
            const float ya = yp[j * 3 + 0];
            const float yb = yp[j * 3 + 1];
            const float yc = yp[j * 3 + 2];
            const float hy = -0.5f * fmaf(yc, yc, fmaf(yb, yb, ya * ya));
            const float m  = fmaf(a, ya, fmaf(bb, yb, fmaf(cc, yc, hy)));
            if (m > rb) { rb = m; bidx = j; }  // in-lane: j ascending
        }
#pragma unroll
        for (int w = 1; w < 8; w <<= 1) {
            const float mo = __shfl_xor(rb, w);
            const int   jo = __shfl_xor(bidx, w);
            if (mo > rb || (mo == rb && jo < bidx)) { rb = mo; bidx = jo; }
        }
        // 3) terms on lane 0, pre-scaled for direct accumulation
        if (lane == 0) {
            const float hx = -0.5f * fmaf(cc, cc, fmaf(bb, bb, a * a));
            float d2 = -2.0f * (rb + hx);
            d2 = fmaxf(d2, 0.0f);
            const float w = __expf(-(d2 * d2) * (1.0f / 0.18f));  // 2*ALPHA^2
            t0 = 0.5f * w * d2;                       // mean over B=2 of sums
            const float nx0 = xn[n * 3 + 0], nx1 = xn[n * 3 + 1], nx2 = xn[n * 3 + 2];
            const float ny0 = yn[(size_t)bidx * 3 + 0];
            const float ny1 = yn[(size_t)bidx * 3 + 1];
            const float ny2 = yn[(size_t)bidx * 3 + 2];
            const float nnx = fmaxf(sqrtf(nx0 * nx0 + nx1 * nx1 + nx2 * nx2), 1e-6f);
            const float nny = fmaxf(sqrtf(ny0 * ny0 + ny1 * ny1 + ny2 * ny2), 1e-6f);
            const float cosv = (nx0 * ny0 + nx1 * ny1 + nx2 * ny2) / (nnx * nny);
            t1 = (1.0f - fabsf(cosv)) * (1.0f / 20000.0f);   // mean over B*N
        }
    }

    __shared__ float r0[256], r1[256];
    r0[threadIdx.x] = t0;
    r1[threadIdx.x] = t1;
    __syncthreads();
    for (int st = 128; st > 0; st >>= 1) {
        if (threadIdx.x < st) {
            r0[threadIdx.x] += r0[threadIdx.x + st];
            r1[threadIdx.x] += r1[threadIdx.x + st];
        }
        __syncthreads();
    }
    if (threadIdx.x == 0) {
        atomicAdd(&out[0], r0[0]);
        atomicAdd(&out[1], r1[0]);
    }
}

extern "C" void kernel_launch(void* const* d_in, const int* in_sizes, int n_in,
                              void* d_out, int out_size, void* d_ws, size_t ws_size,
                              hipStream_t stream)
{
    const float* pred_pts = (const float*)d_in[0];
    const float* pred_nrm = (const float*)d_in[1];
    const float* targ_pts = (const float*)d_in[2];
    const float* targ_nrm = (const float*)d_in[3];
    float* out = (float*)d_out;

    const int BXCH = (NPTS + 31) / 32;   // 313 blocks per combo in pass B

    float* wsM = (float*)d_ws;           // 4*NS*NPTS f32 = 6.4 MB (ws ~256 MB)

    hipMemsetAsync(out, 0, 2 * sizeof(float), stream);

    dim3 gA(AXCH, NS, 4);                // 1600 blocks (R2-measured geometry)
    knn_max<<<gA, 256, 0, stream>>>(pred_pts, targ_pts, wsM);

    dim3 gB(BXCH, 4);
    finalize<<<gB, 256, 0, stream>>>(pred_pts, pred_nrm, targ_pts, targ_nrm,
                                     wsM, out);
}

// Round 12
// 80.994 us; speedup vs baseline: 1.0562x; 1.0562x over previous
//
#include <hip/hip_runtime.h>
#include <math.h>

#define NPTS 10000
#define XPT 4              // x-points per thread (register-safe; XPT>=6 taxed)
#define AXCH 10            // 10 * 256 * 4 = 10240 >= 10000
#define NS 10              // slices -- fewest slices = fastest knn (R1-measured)
#define SLICE 1000         // NPTS / NS
#define TILE 500           // y-points per LDS stage (float4 = 8 KB)

// ---------------------------------------------------------------------------
// Pass A (exact R1-proposal structure, measured ~28us): per (combo, slice,
// x-chunk) max of m_j = dot(x,y_j) - 0.5*|y_j|^2 (equiv. min d2). All-scalar
// fmaf + max3; two 500-y LDS stages per slice; broadcast b128 reads.
// ---------------------------------------------------------------------------
__global__ __launch_bounds__(256) void knn_max(
    const float* __restrict__ pred_pts, const float* __restrict__ targ_pts,
    float* __restrict__ wsM)
{
    const int c   = blockIdx.z;
    const int dir = c >> 1, b = c & 1;
    const float* xp = (dir == 0 ? targ_pts : pred_pts) + (size_t)b * NPTS * 3;
    const float* yp = (dir == 0 ? pred_pts : targ_pts) + (size_t)b * NPTS * 3;
    const int s = blockIdx.y;
    const int base = blockIdx.x * (256 * XPT) + threadIdx.x;

    __shared__ float4 sy[TILE];

    float xx[XPT][3];
#pragma unroll
    for (int k = 0; k < XPT; ++k) {
        const int n = base + k * 256;
        const int nn = (n < NPTS) ? n : (NPTS - 1);   // clamp; discard on store
        xx[k][0] = xp[nn * 3 + 0];
        xx[k][1] = xp[nn * 3 + 1];
        xx[k][2] = xp[nn * 3 + 2];
    }
    float best[XPT];
#pragma unroll
    for (int k = 0; k < XPT; ++k) best[k] = -1e30f;

    const int jstart = s * SLICE, jend = jstart + SLICE;
    for (int t0 = jstart; t0 < jend; t0 += TILE) {
        __syncthreads();   // protect LDS from previous pass readers
        for (int j = threadIdx.x; j < TILE; j += 256) {
            const float a  = yp[(t0 + j) * 3 + 0];
            const float bb = yp[(t0 + j) * 3 + 1];
            const float cc = yp[(t0 + j) * 3 + 2];
            // hy via explicit fmaf chain so finalize reproduces it bit-exactly
            sy[j] = make_float4(a, bb, cc,
                                -0.5f * fmaf(cc, cc, fmaf(bb, bb, a * a)));
        }
        __syncthreads();
#pragma unroll 4
        for (int j = 0; j < TILE; j += 2) {
            const float4 Y0 = sy[j];           // broadcast: conflict-free
            const float4 Y1 = sy[j + 1];
#pragma unroll
            for (int k = 0; k < XPT; ++k) {
                const float ma = fmaf(xx[k][0], Y0.x,
                                 fmaf(xx[k][1], Y0.y,
                                 fmaf(xx[k][2], Y0.z, Y0.w)));
                const float mb = fmaf(xx[k][0], Y1.x,
                                 fmaf(xx[k][1], Y1.y,
                                 fmaf(xx[k][2], Y1.z, Y1.w)));
                best[k] = fmaxf(fmaxf(best[k], ma), mb);   // -> v_max3_f32
            }
        }
    }

#pragma unroll
    for (int k = 0; k < XPT; ++k) {
        const int n = base + k * 256;
        if (n < NPTS)
            wsM[((size_t)c * NS + s) * NPTS + n] = best[k];   // coalesced
    }
}

// ---------------------------------------------------------------------------
// Pass B: 16-lane group per x-point (16 x per 256-thread block).
//   1) slice-select: lanes 0..NS-1 read one partial each, 4-step butterfly,
//      tie -> smaller s.
//   2) lane-parallel rescan of the winning slice (63 iters), identical fmaf
//      chain -> bit-consistent with pass A; strict > ascending j + cross-lane
//      tie -> smaller j == exact first-occurrence argmax.
//   3) lane 0: Welsch + normal-cosine terms; block-reduce; wsB store.
// ---------------------------------------------------------------------------
__global__ __launch_bounds__(256) void finalize(
    const float* __restrict__ pred_pts, const float* __restrict__ pred_nrm,
    const float* __restrict__ targ_pts, const float* __restrict__ targ_nrm,
    const float* __restrict__ wsM, float2* __restrict__ wsB)
{
    const int c   = blockIdx.y;
    const int dir = c >> 1, b = c & 1;
    const float* xp = (dir == 0 ? targ_pts : pred_pts) + (size_t)b * NPTS * 3;
    const float* xn = (dir == 0 ? targ_nrm : pred_nrm) + (size_t)b * NPTS * 3;
    const float* yp = (dir == 0 ? pred_pts : targ_pts) + (size_t)b * NPTS * 3;
    const float* yn = (dir == 0 ? pred_nrm : targ_nrm) + (size_t)b * NPTS * 3;

    const int lane = threadIdx.x & 15;
    const int n = blockIdx.x * 16 + (threadIdx.x >> 4);

    float t0 = 0.f, t1 = 0.f;
    if (n < NPTS) {
        // 1) slice select (lanes 0..NS-1 active)
        float bm = -1e30f;
        int   bs = 1 << 30;
        if (lane < NS) {
            bm = wsM[((size_t)c * NS + lane) * NPTS + n];
            bs = lane;
        }
#pragma unroll
        for (int w = 1; w < 16; w <<= 1) {
            const float mo = __shfl_xor(bm, w, 16);
            const int   so = __shfl_xor(bs, w, 16);
            if (mo > bm || (mo == bm && so < bs)) { bm = mo; bs = so; }
        }
        // 2) rescan winning slice
        const float a  = xp[n * 3 + 0];
        const float bb = xp[n * 3 + 1];
        const float cc = xp[n * 3 + 2];
        const int j0 = bs * SLICE;
        float rb = -1e30f;
        int bidx = 1 << 30;
        for (int j = j0 + lane; j < j0 + SLICE; j += 16) {
            const float ya = yp[j * 3 + 0];
            const float yb = yp[j * 3 + 1];
            const float yc = yp[j * 3 + 2];
            const float hy = -0.5f * fmaf(yc, yc, fmaf(yb, yb, ya * ya));
            const float m  = fmaf(a, ya, fmaf(bb, yb, fmaf(cc, yc, hy)));
            if (m > rb) { rb = m; bidx = j; }  // in-lane: j ascending
        }
#pragma unroll
        for (int w = 1; w < 16; w <<= 1) {
            const float mo = __shfl_xor(rb, w, 16);
            const int   jo = __shfl_xor(bidx, w, 16);
            if (mo > rb || (mo == rb && jo < bidx)) { rb = mo; bidx = jo; }
        }
        // 3) terms on lane 0 only
        if (lane == 0) {
            const float hx = -0.5f * fmaf(cc, cc, fmaf(bb, bb, a * a));
            float d2 = -2.0f * (rb + hx);
            d2 = fmaxf(d2, 0.0f);
            const float w = __expf(-(d2 * d2) * (1.0f / 0.18f));  // 2*ALPHA^2
            t0 = w * d2;
            const float nx0 = xn[n * 3 + 0], nx1 = xn[n * 3 + 1], nx2 = xn[n * 3 + 2];
            const float ny0 = yn[(size_t)bidx * 3 + 0];
            const float ny1 = yn[(size_t)bidx * 3 + 1];
            const float ny2 = yn[(size_t)bidx * 3 + 2];
            const float nnx = fmaxf(sqrtf(nx0 * nx0 + nx1 * nx1 + nx2 * nx2), 1e-6f);
            const float nny = fmaxf(sqrtf(ny0 * ny0 + ny1 * ny1 + ny2 * ny2), 1e-6f);
            const float cosv = (nx0 * ny0 + nx1 * ny1 + nx2 * ny2) / (nnx * nny);
            t1 = 1.0f - fabsf(cosv);
        }
    }

    __shared__ float r0[256], r1[256];
    r0[threadIdx.x] = t0;
    r1[threadIdx.x] = t1;
    __syncthreads();
    for (int st = 128; st > 0; st >>= 1) {
        if (threadIdx.x < st) {
            r0[threadIdx.x] += r0[threadIdx.x + st];
            r1[threadIdx.x] += r1[threadIdx.x + st];
        }
        __syncthreads();
    }
    if (threadIdx.x == 0)
        wsB[blockIdx.y * gridDim.x + blockIdx.x] = make_float2(r0[0], r1[0]);
}

// ---------------------------------------------------------------------------
// Final deterministic reduction of the 2500 block partials.
// ---------------------------------------------------------------------------
__global__ __launch_bounds__(256) void reduce_final(
    const float2* __restrict__ wsB, int nblocks, float* __restrict__ out)
{
    __shared__ float r0[256], r1[256];
    const int t = threadIdx.x;
    float s0 = 0.f, s1 = 0.f;
    for (int i = t; i < nblocks; i += 256) {
        const float2 v = wsB[i];
        s0 += v.x;
        s1 += v.y;
    }
    r0[t] = s0; r1[t] = s1;
    __syncthreads();
    for (int st = 128; st > 0; st >>= 1) {
        if (t < st) { r0[t] += r0[t + st]; r1[t] += r1[t + st]; }
        __syncthreads();
    }
    if (t == 0) {
        out[0] = 0.5f * r0[0];                 // mean over B=2 of per-batch sums
        out[1] = r1[0] * (1.0f / 20000.0f);    // mean over B*N, both dirs
    }
}

extern "C" void kernel_launch(void* const* d_in, const int* in_sizes, int n_in,
                              void* d_out, int out_size, void* d_ws, size_t ws_size,
                              hipStream_t stream)
{
    const float* pred_pts = (const float*)d_in[0];
    const float* pred_nrm = (const float*)d_in[1];
    const float* targ_pts = (const float*)d_in[2];
    const float* targ_nrm = (const float*)d_in[3];
    float* out = (float*)d_out;

    const int BXCH = (NPTS + 15) / 16;   // 625 blocks per combo in pass B

    float* wsM = (float*)d_ws;           // 4*NS*NPTS f32 = 1.6 MB
    float2* wsB = (float2*)((char*)d_ws + (size_t)4 * NS * NPTS * sizeof(float));

    dim3 gA(AXCH, NS, 4);                // 400 blocks (R1-measured: ~28us)
    knn_max<<<gA, 256, 0, stream>>>(pred_pts, targ_pts, wsM);

    dim3 gB(BXCH, 4);
    finalize<<<gB, 256, 0, stream>>>(pred_pts, pred_nrm, targ_pts, targ_nrm,
                                     wsM, wsB);

    reduce_final<<<1, 256, 0, stream>>>(wsB, BXCH * 4, out);
}